// Round 8
// baseline (234.576 us; speedup 1.0000x reference)
//
#include <hip/hip_runtime.h>
#include <math.h>

// Problem constants
#define B_   4
#define N_   4096
#define K_   32
#define C_   192
#define CH_  195          // C + 3 (logical GEMM K)
#define KPAD 224          // 7 x 32 ; rows: 0..2=dp, 3..7=0, 8..199=channels, 200..223=0
#define PTS  2            // points per group
#define NKT  7            // K-tiles
#define NNT  4            // N-tiles (64 cols / 16)
#define NGROUPS ((B_ * N_) / PTS)   // 8192 point-groups
#define GPX  (NGROUPS / 8)          // 1024 groups per XCD
#define BPX  96                     // persistent blocks per XCD (3 per CU)
#define GRID (8 * BPX)              // 768

using half8  = __attribute__((ext_vector_type(8))) _Float16;
using half2v = __attribute__((ext_vector_type(2))) _Float16;
using f32x4  = __attribute__((ext_vector_type(4))) float;

// Module-static device scratch (NOT d_ws — R4 post-mortem: overran ws_size).
__device__ _Float16 g_Wp[C_ * KPAD];                    // 86016 B (rows pre-scaled by BN inv)
__device__ _Float16 g_xT[(size_t)B_ * N_ * C_];         // 6291456 B

// 16-lane max reduction on the VALU via DPP (no DS pipe)
__device__ __forceinline__ float dpp_max16(float v) {
    int s;
    s = __builtin_amdgcn_update_dpp(0, __float_as_int(v), 0xB1,  0xF, 0xF, true); // quad xor1
    v = fmaxf(v, __int_as_float(s));
    s = __builtin_amdgcn_update_dpp(0, __float_as_int(v), 0x4E,  0xF, 0xF, true); // quad xor2
    v = fmaxf(v, __int_as_float(s));
    s = __builtin_amdgcn_update_dpp(0, __float_as_int(v), 0x141, 0xF, 0xF, true); // half-mirror
    v = fmaxf(v, __int_as_float(s));
    s = __builtin_amdgcn_update_dpp(0, __float_as_int(v), 0x140, 0xF, 0xF, true); // row mirror
    v = fmaxf(v, __int_as_float(s));
    return v;
}

// ---- fused prep: blocks 0..1023 transpose x -> g_xT ; blocks 1024.. convert W ----
__global__ __launch_bounds__(256) void prep(const float* __restrict__ x,
                                            const float* __restrict__ W,
                                            const float* __restrict__ gamma_,
                                            const float* __restrict__ rvar) {
    __shared__ float s[32][97];
    const int tid = threadIdx.x;
    if (blockIdx.x < 1024) {
        const int bi = blockIdx.x;
        const int b  = bi >> 8;
        const int c0 = ((bi >> 7) & 1) * 96;
        const int n0 = (bi & 127) * 32;
#pragma unroll
        for (int it = 0; it < 3; ++it) {
            const int c  = it * 32 + (tid >> 3);
            const int n4 = (tid & 7) * 4;
            const float4 v = *(const float4*)(x + ((size_t)b * C_ + c0 + c) * N_ + n0 + n4);
            s[n4 + 0][c] = v.x; s[n4 + 1][c] = v.y; s[n4 + 2][c] = v.z; s[n4 + 3][c] = v.w;
        }
        __syncthreads();
#pragma unroll
        for (int it = 0; it < 2; ++it) {
            const int t = it * 256 + tid;
            if (t < 32 * 12) {
                const int n  = t / 12;
                const int ch = t - n * 12;
                half8 v;
#pragma unroll
                for (int jj = 0; jj < 8; ++jj) v[jj] = (_Float16)s[n][ch * 8 + jj];
                *(half8*)(g_xT + ((size_t)b * N_ + n0 + n) * C_ + c0 + ch * 8) = v;
            }
        }
    } else {
        const int i = (blockIdx.x - 1024) * 256 + tid;
        if (i < C_ * KPAD) {
            const int o = i / KPAD, r = i - o * KPAD;
            const float inv = gamma_[o] * rsqrtf(rvar[o] + 1e-5f);  // BN scale folded into W
            float v = 0.0f;
            if (r < 3)                  v = W[o * CH_ + r];
            else if (r >= 8 && r < 200) v = W[o * CH_ + 3 + (r - 8)];
            g_Wp[i] = (_Float16)(v * inv);
        }
    }
}

// ---- persistent fused kernel: 768 blocks, each grid-strides over ~11 groups ----
__global__ __launch_bounds__(256, 3) void la_mfma(
    const float* __restrict__ p,      // [B,N,3]
    const int*   __restrict__ idx,    // [B,N,K]
    const float* __restrict__ gamma_,
    const float* __restrict__ beta_,
    const float* __restrict__ rmean,
    const float* __restrict__ rvar,
    float* __restrict__ out)          // [B,C,N]
{
    __shared__ _Float16 hb[NKT * NNT * 64 * 8];   // 28672 B, B-fragment order
    __shared__ float s_bias[C_], s_fr[32], s_out[C_ * PTS];

    const int tid  = threadIdx.x;
    const int lane = tid & 63;
    const int w    = tid >> 6;
    const int l15  = lane & 15;
    const int quad = lane >> 4;

    // ---- once-per-block init ----
    if (tid < C_) {
        const float inv = gamma_[tid] * rsqrtf(rvar[tid] + 1e-5f);
        s_bias[tid] = beta_[tid] - rmean[tid] * inv;
    }
    // s_fr[f] = (50 / 2pi) * 500^(-f/32)   (v_sin takes revolutions)
    if (tid < 32) s_fr[tid] = 7.9577471546f * exp2f(-(float)tid * 0.2801808715263400f);

    // W a-frags live in registers for the whole kernel (21 x half8 = 84 VGPRs)
    half8 areg[3][NKT];
#pragma unroll
    for (int i = 0; i < 3; ++i) {
        const int m = (w * 3 + i) * 16 + l15;
#pragma unroll
        for (int kt = 0; kt < NKT; ++kt)
            areg[i][kt] = *(const half8*)(g_Wp + (size_t)m * KPAD + kt * 32 + quad * 8);
    }
    __syncthreads();

    float sfr[8];                     // per-thread frequency set (chunk-invariant)
#pragma unroll
    for (int jj = 0; jj < 8; ++jj) sfr[jj] = s_fr[quad * 8 + jj];

    // XCD-partitioned persistent loop: block handles groups of ONE batch-half
    const int xcd = blockIdx.x & 7;
    const int loc = blockIdx.x >> 3;      // 0..95
    const int colB = w * 16 + l15;        // phase-B column (n-tile = w)
    const int ptB  = colB >> 5;
    const int kB   = colB & 31;

    for (int gl = loc; gl < GPX; gl += BPX) {
        const int grp = xcd * GPX + gl;
        const int bn0 = grp * PTS;
        const int b   = bn0 >> 12;
        const int n0  = bn0 & (N_ - 1);

        // ---- Phase B: gather + PosPool embed -> hb (conflict-free frag order) ----
        {
            const int gp = bn0 + ptB;
            const int j  = idx[(size_t)gp * K_ + kB];
            const float d0 = p[(size_t)(b * N_ + j) * 3 + 0] - p[(size_t)gp * 3 + 0];
            const float d1 = p[(size_t)(b * N_ + j) * 3 + 1] - p[(size_t)gp * 3 + 1];
            const float d2 = p[(size_t)(b * N_ + j) * 3 + 2] - p[(size_t)gp * 3 + 2];
            const _Float16* xh = g_xT + ((size_t)b * N_ + j) * C_;

#pragma unroll
            for (int i6 = 0; i6 < 6; ++i6) {
                const int chunk = quad + 4 * i6;           // 0..23
                const half8 v = *(const half8*)(xh + chunk * 8);
                const float dd  = (chunk < 8) ? d0 : ((chunk < 16) ? d1 : d2);
                const float off = (chunk & 4) ? 0.25f : 0.0f;   // cos = sin(+1/4 rev)
                half8 hv;
#pragma unroll
                for (int jj = 0; jj < 8; jj += 2) {
                    const float pe0 = __builtin_amdgcn_sinf(fmaf(dd, sfr[jj],     off));
                    const float pe1 = __builtin_amdgcn_sinf(fmaf(dd, sfr[jj + 1], off));
                    const half2v pe2 = __builtin_bit_cast(half2v, __builtin_amdgcn_cvt_pkrtz(pe0, pe1));
                    half2v v2; v2[0] = v[jj]; v2[1] = v[jj + 1];
                    const half2v r2 = pe2 * v2 + pe2;   // v_pk_fma_f16: pe*(x+1)
                    hv[jj] = r2[0]; hv[jj + 1] = r2[1];
                }
                const int ro = chunk + 1;               // channel octets 1..24
                const int kt = ro >> 2, kq = ro & 3;
                *(half8*)(&hb[(size_t)((kt * NNT + w) * 64 + kq * 16 + l15) * 8]) = hv;
            }
            if (quad == 0) {        // octet 0: dp rows 0..2 + zeros
                half8 hv0 = (half8)(_Float16)0.0f;
                hv0[0] = (_Float16)d0; hv0[1] = (_Float16)d1; hv0[2] = (_Float16)d2;
                *(half8*)(&hb[(size_t)((0 * NNT + w) * 64 + 0 * 16 + l15) * 8]) = hv0;
            } else {                // octets 25..27: zero rows 200..223
                const int ro = 24 + quad;
                const int kt = ro >> 2, kq = ro & 3;
                *(half8*)(&hb[(size_t)((kt * NNT + w) * 64 + kq * 16 + l15) * 8]) = (half8)(_Float16)0.0f;
            }
        }
        __syncthreads();   // A: hb written

        // ---- Phase C: MFMA, A from registers ----
        f32x4 acc[3][4];
#pragma unroll
        for (int i = 0; i < 3; ++i)
#pragma unroll
            for (int t = 0; t < 4; ++t) acc[i][t] = (f32x4)0.0f;

#pragma unroll
        for (int kt = 0; kt < NKT; ++kt) {
            half8 bf[4];
#pragma unroll
            for (int t = 0; t < 4; ++t)
                bf[t] = *(const half8*)(&hb[(size_t)((kt * NNT + t) * 64 + lane) * 8]);
#pragma unroll
            for (int i = 0; i < 3; ++i)
#pragma unroll
                for (int t = 0; t < 4; ++t)
                    acc[i][t] = __builtin_amdgcn_mfma_f32_16x16x32_f16(areg[i][kt], bf[t], acc[i][t], 0, 0, 0);
        }
        __syncthreads();   // B: hb reads done

        // ---- Epilogue: max over k (bias is k-invariant -> add after max) ----
#pragma unroll
        for (int i = 0; i < 3; ++i) {
            const int mbase = (w * 3 + i) * 16 + quad * 4;
#pragma unroll
            for (int pt = 0; pt < PTS; ++pt) {
                const f32x4 va = acc[i][2 * pt];
                const f32x4 vb = acc[i][2 * pt + 1];
#pragma unroll
                for (int r = 0; r < 4; ++r) {
                    float v = fmaxf(va[r], vb[r]);
                    v = dpp_max16(v);
                    if (l15 == 0) {
                        const int m = mbase + r;
                        s_out[m * PTS + pt] = fmaxf(v + s_bias[m], 0.0f);
                    }
                }
            }
        }
        __syncthreads();   // C: s_out written

        if (tid < C_) {
            const float2 o2 = *(const float2*)(&s_out[tid * PTS]);
            *(float2*)(&out[((size_t)b * C_ + tid) * N_ + n0]) = o2;
        }
    }
}

extern "C" void kernel_launch(void* const* d_in, const int* in_sizes, int n_in,
                              void* d_out, int out_size, void* d_ws, size_t ws_size,
                              hipStream_t stream) {
    (void)in_sizes; (void)n_in; (void)out_size; (void)d_ws; (void)ws_size;
    const float* p      = (const float*)d_in[0];
    const float* x      = (const float*)d_in[1];
    const int*   idx    = (const int*)d_in[2];
    const float* W      = (const float*)d_in[3];
    const float* gamma_ = (const float*)d_in[4];
    const float* beta_  = (const float*)d_in[5];
    const float* rmean  = (const float*)d_in[6];
    const float* rvar   = (const float*)d_in[7];
    float* out = (float*)d_out;

    prep<<<1024 + (C_ * KPAD + 255) / 256, 256, 0, stream>>>(x, W, gamma_, rvar);
    la_mfma<<<GRID, 256, 0, stream>>>(p, idx, gamma_, beta_, rmean, rvar, out);
}

// Round 9
// 169.926 us; speedup vs baseline: 1.3805x; 1.3805x over previous
//
#include <hip/hip_runtime.h>
#include <math.h>

// Problem constants
#define B_   4
#define N_   4096
#define K_   32
#define C_   192
#define CH_  195          // C + 3 (logical GEMM K)
#define KPAD 224          // 7 x 32 ; rows: 0..2=dp, 3..7=0, 8..199=channels, 200..223=0
#define PTS  2            // points per block
#define NKT  7            // K-tiles
#define NNT  4            // N-tiles (64 cols / 16)
#define GRID ((B_ * N_) / PTS)   // 8192 blocks, dense dispatch (locality mechanism!)

using half8  = __attribute__((ext_vector_type(8))) _Float16;
using half2v = __attribute__((ext_vector_type(2))) _Float16;
using f32x4  = __attribute__((ext_vector_type(4))) float;

// Module-static device scratch (NOT d_ws — R4 post-mortem: overran ws_size).
__device__ _Float16 g_Wp[C_ * KPAD];                    // 86016 B (rows pre-scaled by BN inv)
__device__ _Float16 g_xT[(size_t)B_ * N_ * C_];         // 6291456 B

// 16-lane max reduction on the VALU via DPP (no DS pipe)
__device__ __forceinline__ float dpp_max16(float v) {
    int s;
    s = __builtin_amdgcn_update_dpp(0, __float_as_int(v), 0xB1,  0xF, 0xF, true); // quad xor1
    v = fmaxf(v, __int_as_float(s));
    s = __builtin_amdgcn_update_dpp(0, __float_as_int(v), 0x4E,  0xF, 0xF, true); // quad xor2
    v = fmaxf(v, __int_as_float(s));
    s = __builtin_amdgcn_update_dpp(0, __float_as_int(v), 0x141, 0xF, 0xF, true); // half-mirror
    v = fmaxf(v, __int_as_float(s));
    s = __builtin_amdgcn_update_dpp(0, __float_as_int(v), 0x140, 0xF, 0xF, true); // row mirror
    v = fmaxf(v, __int_as_float(s));
    return v;
}

// ---- fused prep: blocks 0..1023 transpose x -> g_xT ; blocks 1024.. convert W ----
__global__ __launch_bounds__(256) void prep(const float* __restrict__ x,
                                            const float* __restrict__ W,
                                            const float* __restrict__ gamma_,
                                            const float* __restrict__ rvar) {
    __shared__ float s[32][97];
    const int tid = threadIdx.x;
    if (blockIdx.x < 1024) {
        const int bi = blockIdx.x;
        const int b  = bi >> 8;
        const int c0 = ((bi >> 7) & 1) * 96;
        const int n0 = (bi & 127) * 32;
#pragma unroll
        for (int it = 0; it < 3; ++it) {
            const int c  = it * 32 + (tid >> 3);
            const int n4 = (tid & 7) * 4;
            const float4 v = *(const float4*)(x + ((size_t)b * C_ + c0 + c) * N_ + n0 + n4);
            s[n4 + 0][c] = v.x; s[n4 + 1][c] = v.y; s[n4 + 2][c] = v.z; s[n4 + 3][c] = v.w;
        }
        __syncthreads();
#pragma unroll
        for (int it = 0; it < 2; ++it) {
            const int t = it * 256 + tid;
            if (t < 32 * 12) {
                const int n  = t / 12;
                const int ch = t - n * 12;
                half8 v;
#pragma unroll
                for (int jj = 0; jj < 8; ++jj) v[jj] = (_Float16)s[n][ch * 8 + jj];
                *(half8*)(g_xT + ((size_t)b * N_ + n0 + n) * C_ + c0 + ch * 8) = v;
            }
        }
    } else {
        const int i = (blockIdx.x - 1024) * 256 + tid;
        if (i < C_ * KPAD) {
            const int o = i / KPAD, r = i - o * KPAD;
            const float inv = gamma_[o] * rsqrtf(rvar[o] + 1e-5f);  // BN scale folded into W
            float v = 0.0f;
            if (r < 3)                  v = W[o * CH_ + r];
            else if (r >= 8 && r < 200) v = W[o * CH_ + 3 + (r - 8)];
            g_Wp[i] = (_Float16)(v * inv);
        }
    }
}

// ---- main fused kernel: one block = 2 points, 256 threads, 5 blocks/CU ----
__global__ __launch_bounds__(256, 5) void la_mfma(
    const float* __restrict__ p,      // [B,N,3]
    const int*   __restrict__ idx,    // [B,N,K]
    const float* __restrict__ gamma_,
    const float* __restrict__ beta_,
    const float* __restrict__ rmean,
    const float* __restrict__ rvar,
    float* __restrict__ out)          // [B,C,N]
{
    __shared__ _Float16 hb[NKT * NNT * 64 * 8];   // 28672 B, B-fragment order
    __shared__ float s_bias[C_], s_fr[32], s_out[C_ * PTS];

    const int tid  = threadIdx.x;
    const int lane = tid & 63;
    const int w    = tid >> 6;
    const int l15  = lane & 15;
    const int quad = lane >> 4;

    // XCD swizzle: keep each XCD inside one batch's xT slice (L2-resident)
    const int q  = blockIdx.x & 7;
    const int sI = blockIdx.x >> 3;
    const int L  = q * (GRID / 8) + sI;
    const int bn0 = L * PTS;
    const int b   = bn0 >> 12;
    const int n0  = bn0 & (N_ - 1);

    if (tid < C_) {
        const float inv = gamma_[tid] * rsqrtf(rvar[tid] + 1e-5f);
        s_bias[tid] = beta_[tid] - rmean[tid] * inv;   // scale part lives in g_Wp
    }
    // s_fr[f] = (50 / 2pi) * 500^(-f/32)   (v_sin takes revolutions)
    if (tid < 32) s_fr[tid] = 7.9577471546f * exp2f(-(float)tid * 0.2801808715263400f);
    __syncthreads();

    // ---- Phase B: conflict-free frag-order build of h tile ----
    {
        const int col = w * 16 + l15;     // n-tile = w
        const int pt  = col >> 5;
        const int k   = col & 31;
        const int gp  = bn0 + pt;
        const int j   = idx[(size_t)gp * K_ + k];
        const float d0 = p[(size_t)(b * N_ + j) * 3 + 0] - p[(size_t)gp * 3 + 0];
        const float d1 = p[(size_t)(b * N_ + j) * 3 + 1] - p[(size_t)gp * 3 + 1];
        const float d2 = p[(size_t)(b * N_ + j) * 3 + 2] - p[(size_t)gp * 3 + 2];
        const _Float16* xh = g_xT + ((size_t)b * N_ + j) * C_;

        // per-thread frequency set is chunk-invariant: f = quad*8 + jj
        float sfr[8];
#pragma unroll
        for (int jj = 0; jj < 8; ++jj) sfr[jj] = s_fr[quad * 8 + jj];

#pragma unroll
        for (int i6 = 0; i6 < 6; ++i6) {
            const int chunk = quad + 4 * i6;           // 0..23
            const half8 v = *(const half8*)(xh + chunk * 8);
            const float dd  = (chunk < 8) ? d0 : ((chunk < 16) ? d1 : d2);
            const float off = (chunk & 4) ? 0.25f : 0.0f;   // cos = sin(+1/4 rev)
            half8 hv;
#pragma unroll
            for (int jj = 0; jj < 8; jj += 2) {
                const float pe0 = __builtin_amdgcn_sinf(fmaf(dd, sfr[jj],     off));
                const float pe1 = __builtin_amdgcn_sinf(fmaf(dd, sfr[jj + 1], off));
                const half2v pe2 = __builtin_bit_cast(half2v, __builtin_amdgcn_cvt_pkrtz(pe0, pe1));
                half2v v2; v2[0] = v[jj]; v2[1] = v[jj + 1];
                const half2v r2 = pe2 * v2 + pe2;   // v_pk_fma_f16: pe*(x+1)
                hv[jj] = r2[0]; hv[jj + 1] = r2[1];
            }
            const int ro = chunk + 1;               // channel octets 1..24
            const int kt = ro >> 2, kq = ro & 3;
            *(half8*)(&hb[(size_t)((kt * NNT + w) * 64 + kq * 16 + l15) * 8]) = hv;
        }
        if (quad == 0) {        // octet 0: dp rows 0..2 + zeros
            half8 hv0 = (half8)(_Float16)0.0f;
            hv0[0] = (_Float16)d0; hv0[1] = (_Float16)d1; hv0[2] = (_Float16)d2;
            *(half8*)(&hb[(size_t)((0 * NNT + w) * 64 + 0 * 16 + l15) * 8]) = hv0;
        } else {                // octets 25..27: zero rows 200..223
            const int ro = 24 + quad;
            const int kt = ro >> 2, kq = ro & 3;
            *(half8*)(&hb[(size_t)((kt * NNT + w) * 64 + kq * 16 + l15) * 8]) = (half8)(_Float16)0.0f;
        }
    }
    __syncthreads();

    // ---- Phase C: MFMA GEMM  y[192 x 64] = Wp[192 x 224] * h[224 x 64] ----
    f32x4 acc[3][4];
#pragma unroll
    for (int i = 0; i < 3; ++i)
#pragma unroll
        for (int t = 0; t < 4; ++t) acc[i][t] = (f32x4)0.0f;

#pragma unroll
    for (int kt = 0; kt < NKT; ++kt) {
        const int k0 = kt * 32 + quad * 8;
        half8 a[3], bf[4];
#pragma unroll
        for (int i = 0; i < 3; ++i) {
            const int m = (w * 3 + i) * 16 + l15;
            a[i] = *(const half8*)(g_Wp + (size_t)m * KPAD + k0);   // L1/L2-hot
        }
#pragma unroll
        for (int t = 0; t < 4; ++t)
            bf[t] = *(const half8*)(&hb[(size_t)((kt * NNT + t) * 64 + lane) * 8]);
#pragma unroll
        for (int i = 0; i < 3; ++i)
#pragma unroll
            for (int t = 0; t < 4; ++t)
                acc[i][t] = __builtin_amdgcn_mfma_f32_16x16x32_f16(a[i], bf[t], acc[i][t], 0, 0, 0);
    }

    // ---- Epilogue: max over 32 neighbors (DPP) -> +bias -> ReLU ----
    // C/D layout: col = lane&15, row = quad*4 + reg ; bias is k-invariant -> after max
#pragma unroll
    for (int i = 0; i < 3; ++i) {
        const int mbase = (w * 3 + i) * 16 + quad * 4;
#pragma unroll
        for (int pt = 0; pt < PTS; ++pt) {
            const f32x4 va = acc[i][2 * pt];
            const f32x4 vb = acc[i][2 * pt + 1];
#pragma unroll
            for (int r = 0; r < 4; ++r) {
                float v = fmaxf(va[r], vb[r]);
                v = dpp_max16(v);
                if (l15 == 0) {
                    const int m = mbase + r;
                    s_out[m * PTS + pt] = fmaxf(v + s_bias[m], 0.0f);
                }
            }
        }
    }
    __syncthreads();

    if (tid < C_) {
        const float2 o2 = *(const float2*)(&s_out[tid * PTS]);
        *(float2*)(&out[((size_t)b * C_ + tid) * N_ + n0]) = o2;
    }
}

extern "C" void kernel_launch(void* const* d_in, const int* in_sizes, int n_in,
                              void* d_out, int out_size, void* d_ws, size_t ws_size,
                              hipStream_t stream) {
    (void)in_sizes; (void)n_in; (void)out_size; (void)d_ws; (void)ws_size;
    const float* p      = (const float*)d_in[0];
    const float* x      = (const float*)d_in[1];
    const int*   idx    = (const int*)d_in[2];
    const float* W      = (const float*)d_in[3];
    const float* gamma_ = (const float*)d_in[4];
    const float* beta_  = (const float*)d_in[5];
    const float* rmean  = (const float*)d_in[6];
    const float* rvar   = (const float*)d_in[7];
    float* out = (float*)d_out;

    prep<<<1024 + (C_ * KPAD + 255) / 256, 256, 0, stream>>>(x, W, gamma_, rvar);
    la_mfma<<<GRID, 256, 0, stream>>>(p, idx, gamma_, beta_, rmean, rvar, out);
}